// Round 5
// baseline (347.760 us; speedup 1.0000x reference)
//
#include <hip/hip_runtime.h>
#include <hip/hip_bf16.h>
#include <math.h>
#include <stdint.h>

// ---------------------------------------------------------------------------
// attention_net (MI355X gfx950)
//   conv1: 2048->128 14x14 s1p1 | conv2: 128->128 ->7x7 s2p1 | conv3: ->4x4
//   All convs: split-bf16 (hi+lo) MFMA 32x32x16, NHWC padded-16x16 A,
//   software-pipelined K loop (load s+1 -> regs, mfma s, regs -> LDS).
//   conv1: K-split 48 partials + reduce. conv2/3: no split, fused epilogue.
//   heads fused into NMS kernel. 7 launches total.
// Output floats: part_imgs[7225344], coords[192], top_prob[48], top_idx[48]
// ---------------------------------------------------------------------------

#define OFF_COORDS 7225344
#define OFF_PROB   7225536
#define OFF_IDX    7225584
#define NA 1614
#define K1TOT 18432

typedef __attribute__((ext_vector_type(8)))  short  short8;
typedef __attribute__((ext_vector_type(16))) float  floatx16;

// ---- unified prep: conv1 A + conv1 B + conv2/3 B + zero d2 pad ------------
// grid: [0,1024)    prep_a  : rpn NCHW -> padded(16x16) NHWC split-bf16
//       [1024,2176) prep_b1 : wd1[co][ci][tap] -> b1[co][tap*2048+ci]
//       [2176,3328) prep_w23: w{2,3}[co][ci][tap] -> b{2,3}[co][tap*128+ci]
//       [3328,3584) zero d2ph/d2pl (conv2 epilogue only writes valid slots)
__global__ __launch_bounds__(256) void k_prep_all(
    const float* __restrict__ rpn,
    const float* __restrict__ wd1,
    const float* __restrict__ wd2,
    const float* __restrict__ wd3,
    __hip_bfloat16* __restrict__ ah,  __hip_bfloat16* __restrict__ al,
    __hip_bfloat16* __restrict__ b1h, __hip_bfloat16* __restrict__ b1l,
    __hip_bfloat16* __restrict__ b2h, __hip_bfloat16* __restrict__ b2l,
    __hip_bfloat16* __restrict__ b3h, __hip_bfloat16* __restrict__ b3l,
    __hip_bfloat16* __restrict__ d2ph, __hip_bfloat16* __restrict__ d2pl)
{
    const int bid = blockIdx.x;
    const int t   = threadIdx.x;
    if (bid < 1024) {
        __shared__ float tile[64][65];
        const int cib  = (bid & 31) * 64;
        const int posb = ((bid >> 5) & 3) * 64;
        const int b    = bid >> 7;
#pragma unroll
        for (int it = 0; it < 16; ++it) {
            int idx  = it * 256 + t;
            int cil  = idx >> 6;
            int posl = idx & 63;
            int pos  = posb + posl;
            int py = pos >> 4, px = pos & 15;
            int y = py - 1, x = px - 1;
            float v = 0.0f;
            if ((unsigned)y < 14u && (unsigned)x < 14u)
                v = rpn[((size_t)(b * 2048 + cib + cil) * 14 + y) * 14 + x];
            tile[cil][posl] = v;
        }
        __syncthreads();
#pragma unroll
        for (int it = 0; it < 16; ++it) {
            int idx  = it * 256 + t;
            int posl = idx >> 6;
            int cil  = idx & 63;
            float v = tile[cil][posl];
            __hip_bfloat16 h = __float2bfloat16(v);
            __hip_bfloat16 l = __float2bfloat16(v - __bfloat162float(h));
            size_t o = (size_t)(b * 256 + posb + posl) * 2048 + cib + cil;
            ah[o] = h; al[o] = l;
        }
    } else if (bid < 2176) {
        int local = bid - 1024;
        int tap = local % 9;
        int co  = local / 9;
#pragma unroll
        for (int i = 0; i < 8; ++i) {
            int ci = i * 256 + t;
            float v = wd1[((size_t)co * 2048 + ci) * 9 + tap];
            __hip_bfloat16 h = __float2bfloat16(v);
            __hip_bfloat16 l = __float2bfloat16(v - __bfloat162float(h));
            size_t o = (size_t)co * K1TOT + tap * 2048 + ci;
            b1h[o] = h; b1l[o] = l;
        }
    } else if (bid < 3328) {
        int local = bid - 2176;          // 0..1151
        int z  = local >= 576;
        int l3 = z ? (local - 576) : local;
        int tap = l3 % 9;
        int co  = (l3 / 9) * 2 + (t >> 7);
        int ci  = t & 127;
        const float* w = z ? wd3 : wd2;
        __hip_bfloat16* bh = z ? b3h : b2h;
        __hip_bfloat16* bl = z ? b3l : b2l;
        float v = w[((size_t)co * 128 + ci) * 9 + tap];
        __hip_bfloat16 h = __float2bfloat16(v);
        __hip_bfloat16 l = __float2bfloat16(v - __bfloat162float(h));
        size_t o = (size_t)co * 1152 + tap * 128 + ci;
        bh[o] = h; bl[o] = l;
    } else {
        const short8 z8 = {0,0,0,0,0,0,0,0};
        int idx = (bid - 3328) * 256 + t;          // [0, 65536)
        if (idx < 32768) ((short8*)d2ph)[idx] = z8;
        else             ((short8*)d2pl)[idx - 32768] = z8;
    }
}

// ---- unified split-bf16 MFMA implicit-GEMM conv, software-pipelined -------
// C[MTOT][128] = A*B ; A[m][k], k=tap*CIN+ci, A from padded NHWC [b][16][16][CIN]
// Block 128m x 128n, 4 waves (2x2 of 64x64), K-stage 32.
// EPI 0: write partial[kc]   1: bias/relu -> dn + padded bf16 hi/lo
// EPI 2: bias/relu -> dn only
template<int POSN, int OW, int STR, int CIN, int MTOT, int EPI>
__global__ __launch_bounds__(256) void k_conv_mfma(
    const short* __restrict__ ah, const short* __restrict__ al,
    const short* __restrict__ bh, const short* __restrict__ bl,
    float* __restrict__ fout,
    __hip_bfloat16* __restrict__ ph, __hip_bfloat16* __restrict__ pl,
    const float* __restrict__ bias, int chunk)
{
    constexpr int KTOT = CIN * 9;
    __shared__ short AsH[128][40];
    __shared__ short AsL[128][40];
    __shared__ short BsH[128][40];
    __shared__ short BsL[128][40];

    const int t     = threadIdx.x;
    const int lane  = t & 63;
    const int w     = t >> 6;
    const int wm    = (w & 1) * 64;
    const int wn    = (w >> 1) * 64;
    const int lm    = lane & 31;
    const int half  = lane >> 5;
    const int mt    = blockIdx.x;
    const int kc    = blockIdx.y;
    const int mbase = mt * 128;
    const int k0    = kc * chunk;
    const int k1    = (k0 + chunk < KTOT) ? (k0 + chunk) : KTOT;

    int arow[2], apos[2]; bool aval[2];
    const int akc = (t & 3) * 8;
#pragma unroll
    for (int i = 0; i < 2; ++i) {
        int row = ((i * 256 + t) >> 2);
        int m   = mbase + row;
        arow[i] = row;
        aval[i] = (m < MTOT);
        int mm = aval[i] ? m : 0;
        int b  = mm / POSN;
        int p  = mm - b * POSN;
        int y  = p / OW;
        int x  = p - y * OW;
        apos[i] = b * 256 + y * STR * 16 + x * STR;
    }

    floatx16 acc[2][2];
#pragma unroll
    for (int mf = 0; mf < 2; ++mf)
#pragma unroll
        for (int nf = 0; nf < 2; ++nf)
#pragma unroll
            for (int r = 0; r < 16; ++r) acc[mf][nf][r] = 0.0f;

    const short8 zero8 = {0, 0, 0, 0, 0, 0, 0, 0};
    short8 rAh[2], rAl[2], rBh[2], rBl[2];

    auto load_stage = [&](int ks) {
        const int tap = ks / CIN;        // stage (32) never straddles a tap
        const int ci0 = ks - tap * CIN;
        const int dy  = tap / 3, dx = tap - dy * 3;
#pragma unroll
        for (int i = 0; i < 2; ++i) {
            if (aval[i]) {
                size_t g = (size_t)(apos[i] + dy * 16 + dx) * CIN + ci0 + akc;
                rAh[i] = *(const short8*)(ah + g);
                rAl[i] = *(const short8*)(al + g);
            } else { rAh[i] = zero8; rAl[i] = zero8; }
        }
#pragma unroll
        for (int i = 0; i < 2; ++i) {
            int n = ((i * 256 + t) >> 2);
            size_t g = (size_t)n * KTOT + ks + akc;
            rBh[i] = *(const short8*)(bh + g);
            rBl[i] = *(const short8*)(bl + g);
        }
    };
    auto store_stage = [&]() {
#pragma unroll
        for (int i = 0; i < 2; ++i) {
            *(short8*)&AsH[arow[i]][akc] = rAh[i];
            *(short8*)&AsL[arow[i]][akc] = rAl[i];
            int n = ((i * 256 + t) >> 2);
            *(short8*)&BsH[n][akc] = rBh[i];
            *(short8*)&BsL[n][akc] = rBl[i];
        }
    };
    auto compute = [&]() {
#pragma unroll
        for (int kst = 0; kst < 2; ++kst) {
            const int koff = kst * 16 + half * 8;
            short8 a_h[2], a_l[2], b_h[2], b_l[2];
#pragma unroll
            for (int mf = 0; mf < 2; ++mf) {
                a_h[mf] = *(const short8*)&AsH[wm + mf * 32 + lm][koff];
                a_l[mf] = *(const short8*)&AsL[wm + mf * 32 + lm][koff];
            }
#pragma unroll
            for (int nf = 0; nf < 2; ++nf) {
                b_h[nf] = *(const short8*)&BsH[wn + nf * 32 + lm][koff];
                b_l[nf] = *(const short8*)&BsL[wn + nf * 32 + lm][koff];
            }
#pragma unroll
            for (int mf = 0; mf < 2; ++mf)
#pragma unroll
                for (int nf = 0; nf < 2; ++nf) {
                    acc[mf][nf] = __builtin_amdgcn_mfma_f32_32x32x16_bf16(
                        a_h[mf], b_h[nf], acc[mf][nf], 0, 0, 0);
                    acc[mf][nf] = __builtin_amdgcn_mfma_f32_32x32x16_bf16(
                        a_h[mf], b_l[nf], acc[mf][nf], 0, 0, 0);
                    acc[mf][nf] = __builtin_amdgcn_mfma_f32_32x32x16_bf16(
                        a_l[mf], b_h[nf], acc[mf][nf], 0, 0, 0);
                }
        }
    };

    // software pipeline: load s+1 overlaps mfma of s
    load_stage(k0);
    store_stage();
    for (int ks = k0 + 32; ks < k1; ks += 32) {
        __syncthreads();
        load_stage(ks);      // issue early; waitcnt lands before store_stage
        compute();           // stage ks-32 from LDS
        __syncthreads();
        store_stage();
    }
    __syncthreads();
    compute();               // last stage

    if constexpr (EPI == 0) {
        float* P = fout + (size_t)kc * MTOT * 128;
#pragma unroll
        for (int mf = 0; mf < 2; ++mf)
#pragma unroll
            for (int nf = 0; nf < 2; ++nf)
#pragma unroll
                for (int r = 0; r < 16; ++r) {
                    int row = (r & 3) + 8 * (r >> 2) + 4 * half;
                    int m = mbase + wm + mf * 32 + row;
                    int n = wn + nf * 32 + lm;
                    if (m < MTOT) P[(size_t)m * 128 + n] = acc[mf][nf][r];
                }
    } else {
#pragma unroll
        for (int mf = 0; mf < 2; ++mf)
#pragma unroll
            for (int nf = 0; nf < 2; ++nf)
#pragma unroll
                for (int r = 0; r < 16; ++r) {
                    int row = (r & 3) + 8 * (r >> 2) + 4 * half;
                    int m = mbase + wm + mf * 32 + row;
                    int n = wn + nf * 32 + lm;
                    if (m < MTOT) {
                        float s = fmaxf(acc[mf][nf][r] + bias[n], 0.0f);
                        fout[(size_t)m * 128 + n] = s;
                        if constexpr (EPI == 1) {
                            int b = m / POSN, p = m - b * POSN;
                            int y = p / OW,   x = p - y * OW;
                            int o = (b * 256 + (y + 1) * 16 + (x + 1)) * 128 + n;
                            __hip_bfloat16 h = __float2bfloat16(s);
                            ph[o] = h;
                            pl[o] = __float2bfloat16(s - __bfloat162float(h));
                        }
                    }
                }
    }
}

// ---- fused reduce (conv1): partials + bias + relu -> NHWC fp32 + padded bf16
template<int POSN, int OWV>
__global__ __launch_bounds__(256) void k_reduce_pad(const float* __restrict__ partial,
                                                    const float* __restrict__ bias,
                                                    float* __restrict__ dn,
                                                    __hip_bfloat16* __restrict__ ph,
                                                    __hip_bfloat16* __restrict__ pl,
                                                    int S)
{
    constexpr int MTOT = 8 * POSN;
    int idx = blockIdx.x * 256 + threadIdx.x;   // < 8*256*128
    int b   = idx >> 15;
    int pos = (idx >> 7) & 255;
    int co  = idx & 127;
    int y = (pos >> 4) - 1;
    int x = (pos & 15) - 1;
    if ((unsigned)y < (unsigned)OWV && (unsigned)x < (unsigned)OWV) {
        int m = b * POSN + y * OWV + x;
        float s = bias[co];
        for (int k = 0; k < S; ++k) s += partial[(size_t)k * MTOT * 128 + m * 128 + co];
        s = fmaxf(s, 0.0f);
        dn[(size_t)m * 128 + co] = s;
        __hip_bfloat16 h = __float2bfloat16(s);
        __hip_bfloat16 l = __float2bfloat16(s - __bfloat162float(h));
        ph[idx] = h; pl[idx] = l;
    } else {
        ph[idx] = __float2bfloat16(0.0f);
        pl[idx] = __float2bfloat16(0.0f);
    }
}

// ---- heads + NMS + top-6 (fused) ------------------------------------------
// Greedy NMS truncated at 6 survivors == 6 rounds of argmax + suppress.
__global__ __launch_bounds__(256) void k_nms_topk(
    const float* __restrict__ d1n, const float* __restrict__ d2n,
    const float* __restrict__ d3n,
    const float* __restrict__ w1, const float* __restrict__ b1,
    const float* __restrict__ w2, const float* __restrict__ b2,
    const float* __restrict__ w3, const float* __restrict__ b3,
    const float* __restrict__ anchors,
    float* __restrict__ out, int* __restrict__ boxes)
{
    __shared__ float ms[NA];
    __shared__ float ay0[NA], ax0[NA], ay1[NA], ax1[NA];
    __shared__ unsigned char picked[NA];
    __shared__ float rv[4]; __shared__ int ri[4];
    __shared__ float win[5];
    int b = blockIdx.x;
    int t = threadIdx.x;
    // heads: compute scores for this batch directly into LDS
    for (int e = t; e < NA; e += 256) {
        const float* d; const float* w; float bias;
        if (e < 1176) {
            int c = e / 196, p = e - c * 196;
            d = d1n + (size_t)(b * 196 + p) * 128; w = w1 + c * 128; bias = b1[c];
        } else if (e < 1470) {
            int e2 = e - 1176; int c = e2 / 49, p = e2 - c * 49;
            d = d2n + (size_t)(b * 49 + p) * 128; w = w2 + c * 128; bias = b2[c];
        } else {
            int e2 = e - 1470; int c = e2 / 16, p = e2 - c * 16;
            d = d3n + (size_t)(b * 16 + p) * 128; w = w3 + c * 128; bias = b3[c];
        }
        float s = bias;
#pragma unroll
        for (int i = 0; i < 32; ++i) {
            float4 dv = ((const float4*)d)[i];
            float4 wv = ((const float4*)w)[i];
            s = fmaf(dv.x, wv.x, s);
            s = fmaf(dv.y, wv.y, s);
            s = fmaf(dv.z, wv.z, s);
            s = fmaf(dv.w, wv.w, s);
        }
        ms[e] = s;
    }
    for (int i = t; i < NA; i += 256) {
        float4 an = ((const float4*)anchors)[i];
        ay0[i] = an.x; ax0[i] = an.y; ay1[i] = an.z; ax1[i] = an.w;
        picked[i] = 0;
    }
    __syncthreads();
    for (int r = 0; r < 6; ++r) {
        float bv = -INFINITY; int bi = NA;
        for (int i = t; i < NA; i += 256) {
            if (!picked[i]) {
                float v = ms[i];
                if (v > bv || (v == bv && i < bi)) { bv = v; bi = i; }
            }
        }
#pragma unroll
        for (int off = 32; off > 0; off >>= 1) {
            float v2 = __shfl_down(bv, off);
            int   i2 = __shfl_down(bi, off);
            if (v2 > bv || (v2 == bv && i2 < bi)) { bv = v2; bi = i2; }
        }
        if ((t & 63) == 0) { rv[t >> 6] = bv; ri[t >> 6] = bi; }
        __syncthreads();
        if (t == 0) {
            bv = rv[0]; bi = ri[0];
            for (int wv = 1; wv < 4; ++wv)
                if (rv[wv] > bv || (rv[wv] == bv && ri[wv] < bi)) { bv = rv[wv]; bi = ri[wv]; }
            picked[bi] = 1;
            win[0] = ay0[bi]; win[1] = ax0[bi]; win[2] = ay1[bi]; win[3] = ax1[bi]; win[4] = bv;
            int o = b * 6 + r;
            out[OFF_COORDS + o * 4 + 0] = ax0[bi];
            out[OFF_COORDS + o * 4 + 1] = ay0[bi];
            out[OFF_COORDS + o * 4 + 2] = ax1[bi];
            out[OFF_COORDS + o * 4 + 3] = ay1[bi];
            out[OFF_PROB + o] = bv;
            out[OFF_IDX  + o] = (float)bi;
            boxes[o * 4 + 0] = (int)ax0[bi];
            boxes[o * 4 + 1] = (int)ay0[bi];
            boxes[o * 4 + 2] = (int)ax1[bi];
            boxes[o * 4 + 3] = (int)ay1[bi];
        }
        __syncthreads();
        float by0 = win[0], bx0 = win[1], by1 = win[2], bx1 = win[3];
        float barea = (by1 - by0) * (bx1 - bx0);
        for (int i = t; i < NA; i += 256) {
            if (picked[i]) continue;
            float ih = fmaxf(fminf(by1, ay1[i]) - fmaxf(by0, ay0[i]), 0.0f);
            float iw = fmaxf(fminf(bx1, ax1[i]) - fmaxf(bx0, ax0[i]), 0.0f);
            float inter = ih * iw;
            float area  = (ay1[i] - ay0[i]) * (ax1[i] - ax0[i]);
            float iou = inter / (barea + area - inter);
            if (iou > 0.25f) ms[i] = -INFINITY;
        }
        __syncthreads();
    }
}

// ---- bilinear crop-resize, flat 1 thread = 1 px ---------------------------
__global__ __launch_bounds__(256) void k_crop(const float* __restrict__ x,
                                              const int* __restrict__ boxes,
                                              float* __restrict__ out)
{
    int lin = blockIdx.x * 256 + threadIdx.x;   // < 144*224*224
    int i    = lin % 224;
    int rest = lin / 224;
    int j    = rest % 224;
    int rc   = rest / 224;
    int c    = rc % 3;
    int br   = rc / 3;
    int b    = br / 6;
    int4 bx = ((const int4*)boxes)[br];
    float tj = (float)j / 223.0f;
    float sy = (float)bx.y + tj * (float)(bx.w - 1 - bx.y);
    int y0i = (int)floorf(sy);
    int y1i = min(y0i + 1, bx.w - 1);
    float wy = sy - (float)y0i;
    float ti = (float)i / 223.0f;
    float sx = (float)bx.x + ti * (float)(bx.z - 1 - bx.x);
    int x0i = (int)floorf(sx);
    int x1i = min(x0i + 1, bx.z - 1);
    float wx = sx - (float)x0i;
    const float* img = x + ((size_t)b * 3 + c) * 448 * 448;
    auto g = [&](int yy, int xx) -> float {
        yy -= 224; xx -= 224;
        if ((unsigned)yy >= 448u || (unsigned)xx >= 448u) return 0.0f;
        return img[(size_t)yy * 448 + xx];
    };
    float g00 = g(y0i, x0i), g01 = g(y0i, x1i);
    float g10 = g(y1i, x0i), g11 = g(y1i, x1i);
    float top = (1.0f - wx) * g00 + wx * g01;
    float bot = (1.0f - wx) * g10 + wx * g11;
    out[lin] = (1.0f - wy) * top + wy * bot;
}

// ---------------------------------------------------------------------------
extern "C" void kernel_launch(void* const* d_in, const int* in_sizes, int n_in,
                              void* d_out, int out_size, void* d_ws, size_t ws_size,
                              hipStream_t stream)
{
    (void)in_sizes; (void)n_in; (void)out_size;
    const float* x    = (const float*)d_in[0];
    const float* rpn  = (const float*)d_in[1];
    const float* anch = (const float*)d_in[2];
    const float* wd1  = (const float*)d_in[3];
    const float* bd1  = (const float*)d_in[4];
    const float* wd2  = (const float*)d_in[5];
    const float* bd2  = (const float*)d_in[6];
    const float* wd3  = (const float*)d_in[7];
    const float* bd3  = (const float*)d_in[8];
    const float* hw1  = (const float*)d_in[9];
    const float* hb1  = (const float*)d_in[10];
    const float* hw2  = (const float*)d_in[11];
    const float* hb2  = (const float*)d_in[12];
    const float* hw3  = (const float*)d_in[13];
    const float* hb3  = (const float*)d_in[14];
    float* out = (float*)d_out;

    char* ws = (char*)d_ws;
    size_t off = 0;
    auto alloc = [&](size_t bytes) -> void* {
        void* p = ws + off;
        off = (off + bytes + 255) & ~(size_t)255;
        return p;
    };
    __hip_bfloat16* ahb  = (__hip_bfloat16*)alloc((size_t)8 * 256 * 2048 * 2);
    __hip_bfloat16* alb  = (__hip_bfloat16*)alloc((size_t)8 * 256 * 2048 * 2);
    __hip_bfloat16* b1h  = (__hip_bfloat16*)alloc((size_t)128 * K1TOT * 2);
    __hip_bfloat16* b1l  = (__hip_bfloat16*)alloc((size_t)128 * K1TOT * 2);
    __hip_bfloat16* b2h  = (__hip_bfloat16*)alloc((size_t)128 * 1152 * 2);
    __hip_bfloat16* b2l  = (__hip_bfloat16*)alloc((size_t)128 * 1152 * 2);
    __hip_bfloat16* b3h  = (__hip_bfloat16*)alloc((size_t)128 * 1152 * 2);
    __hip_bfloat16* b3l  = (__hip_bfloat16*)alloc((size_t)128 * 1152 * 2);
    __hip_bfloat16* d1ph = (__hip_bfloat16*)alloc((size_t)8 * 256 * 128 * 2);
    __hip_bfloat16* d1pl = (__hip_bfloat16*)alloc((size_t)8 * 256 * 128 * 2);
    __hip_bfloat16* d2ph = (__hip_bfloat16*)alloc((size_t)8 * 256 * 128 * 2);
    __hip_bfloat16* d2pl = (__hip_bfloat16*)alloc((size_t)8 * 256 * 128 * 2);
    float* d1n  = (float*)alloc((size_t)8 * 196 * 128 * 4);
    float* d2n  = (float*)alloc((size_t)8 * 49 * 128 * 4);
    float* d3n  = (float*)alloc((size_t)8 * 16 * 128 * 4);
    int*  boxes = (int*)alloc((size_t)8 * 6 * 4 * 4);
    size_t avail = (ws_size > off) ? (ws_size - off) : 0;
    float* P = (float*)(ws + off);

    // conv1 K-split (chunk must be a multiple of 32)
    int S1 = 48;
    if (avail < (size_t)48 * 1568 * 128 * 4) S1 = 32;
    if (avail < (size_t)32 * 1568 * 128 * 4) S1 = 16;
    int chunk1 = K1TOT / S1;        // 384 / 576 / 1152

    k_prep_all<<<dim3(3584), 256, 0, stream>>>(rpn, wd1, wd2, wd3,
        ahb, alb, b1h, b1l, b2h, b2l, b3h, b3l, d2ph, d2pl);

    // conv1: M=1568, CIN=2048, K-split -> partials
    k_conv_mfma<196, 14, 1, 2048, 1568, 0><<<dim3(13, S1), 256, 0, stream>>>(
        (const short*)ahb, (const short*)alb, (const short*)b1h, (const short*)b1l,
        P, nullptr, nullptr, nullptr, chunk1);
    k_reduce_pad<196, 14><<<dim3(1024), 256, 0, stream>>>(P, bd1, d1n, d1ph, d1pl, S1);

    // conv2: M=392, no K-split, fused bias/relu/split epilogue
    k_conv_mfma<49, 7, 2, 128, 392, 1><<<dim3(4, 1), 256, 0, stream>>>(
        (const short*)d1ph, (const short*)d1pl, (const short*)b2h, (const short*)b2l,
        d2n, d2ph, d2pl, bd2, 1152);

    // conv3: M=128, no K-split, fused bias/relu epilogue
    k_conv_mfma<16, 4, 2, 128, 128, 2><<<dim3(1, 1), 256, 0, stream>>>(
        (const short*)d2ph, (const short*)d2pl, (const short*)b3h, (const short*)b3l,
        d3n, nullptr, nullptr, bd3, 1152);

    // heads + NMS + top6 (fused)
    k_nms_topk<<<dim3(8), 256, 0, stream>>>(d1n, d2n, d3n,
        hw1, hb1, hw2, hb2, hw3, hb3, anch, out, boxes);

    k_crop<<<dim3(28224), 256, 0, stream>>>(x, boxes, out);
}

// Round 6
// 304.852 us; speedup vs baseline: 1.1408x; 1.1408x over previous
//
#include <hip/hip_runtime.h>
#include <hip/hip_bf16.h>
#include <math.h>
#include <stdint.h>

// ---------------------------------------------------------------------------
// attention_net (MI355X gfx950)
//   conv1: 2048->128 14x14 s1p1 | conv2: 128->128 ->7x7 s2p1 | conv3: ->4x4
//   All convs: split-bf16 (hi+lo) MFMA 32x32x16, NHWC padded-16x16 A,
//   software-pipelined K loop. K-split partials + fused reduce epilogues.
//   heads fused into NMS kernel with 16-lane-per-score parallel dots.
// Output floats: part_imgs[7225344], coords[192], top_prob[48], top_idx[48]
// ---------------------------------------------------------------------------

#define OFF_COORDS 7225344
#define OFF_PROB   7225536
#define OFF_IDX    7225584
#define NA 1614
#define K1TOT 18432

typedef __attribute__((ext_vector_type(8)))  short  short8;
typedef __attribute__((ext_vector_type(16))) float  floatx16;

// ---- unified prep: conv1 A + conv1 B + conv2/3 B --------------------------
// grid: [0,1024)    prep_a  : rpn NCHW -> padded(16x16) NHWC split-bf16
//       [1024,2176) prep_b1 : wd1[co][ci][tap] -> b1[co][tap*2048+ci]
//       [2176,3328) prep_w23: w{2,3}[co][ci][tap] -> b{2,3}[co][tap*128+ci]
__global__ __launch_bounds__(256) void k_prep_all(
    const float* __restrict__ rpn,
    const float* __restrict__ wd1,
    const float* __restrict__ wd2,
    const float* __restrict__ wd3,
    __hip_bfloat16* __restrict__ ah,  __hip_bfloat16* __restrict__ al,
    __hip_bfloat16* __restrict__ b1h, __hip_bfloat16* __restrict__ b1l,
    __hip_bfloat16* __restrict__ b2h, __hip_bfloat16* __restrict__ b2l,
    __hip_bfloat16* __restrict__ b3h, __hip_bfloat16* __restrict__ b3l)
{
    const int bid = blockIdx.x;
    const int t   = threadIdx.x;
    if (bid < 1024) {
        __shared__ float tile[64][65];
        const int cib  = (bid & 31) * 64;
        const int posb = ((bid >> 5) & 3) * 64;
        const int b    = bid >> 7;
#pragma unroll
        for (int it = 0; it < 16; ++it) {
            int idx  = it * 256 + t;
            int cil  = idx >> 6;
            int posl = idx & 63;
            int pos  = posb + posl;
            int py = pos >> 4, px = pos & 15;
            int y = py - 1, x = px - 1;
            float v = 0.0f;
            if ((unsigned)y < 14u && (unsigned)x < 14u)
                v = rpn[((size_t)(b * 2048 + cib + cil) * 14 + y) * 14 + x];
            tile[cil][posl] = v;
        }
        __syncthreads();
#pragma unroll
        for (int it = 0; it < 16; ++it) {
            int idx  = it * 256 + t;
            int posl = idx >> 6;
            int cil  = idx & 63;
            float v = tile[cil][posl];
            __hip_bfloat16 h = __float2bfloat16(v);
            __hip_bfloat16 l = __float2bfloat16(v - __bfloat162float(h));
            size_t o = (size_t)(b * 256 + posb + posl) * 2048 + cib + cil;
            ah[o] = h; al[o] = l;
        }
    } else if (bid < 2176) {
        int local = bid - 1024;
        int tap = local % 9;
        int co  = local / 9;
#pragma unroll
        for (int i = 0; i < 8; ++i) {
            int ci = i * 256 + t;
            float v = wd1[((size_t)co * 2048 + ci) * 9 + tap];
            __hip_bfloat16 h = __float2bfloat16(v);
            __hip_bfloat16 l = __float2bfloat16(v - __bfloat162float(h));
            size_t o = (size_t)co * K1TOT + tap * 2048 + ci;
            b1h[o] = h; b1l[o] = l;
        }
    } else {
        int local = bid - 2176;          // 0..1151
        int z  = local >= 576;
        int l3 = z ? (local - 576) : local;
        int tap = l3 % 9;
        int co  = (l3 / 9) * 2 + (t >> 7);
        int ci  = t & 127;
        const float* w = z ? wd3 : wd2;
        __hip_bfloat16* bh = z ? b3h : b2h;
        __hip_bfloat16* bl = z ? b3l : b2l;
        float v = w[((size_t)co * 128 + ci) * 9 + tap];
        __hip_bfloat16 h = __float2bfloat16(v);
        __hip_bfloat16 l = __float2bfloat16(v - __bfloat162float(h));
        size_t o = (size_t)co * 1152 + tap * 128 + ci;
        bh[o] = h; bl[o] = l;
    }
}

// ---- unified split-bf16 MFMA implicit-GEMM conv, software-pipelined -------
// C[MTOT][128] = A*B ; A[m][k], k=tap*CIN+ci, A from padded NHWC [b][16][16][CIN]
// Block 128m x 128n, 4 waves (2x2 of 64x64), K-stage 32, K-split grid.y ->
// deterministic partial[kc][m][n].
template<int POSN, int OW, int STR, int CIN, int MTOT>
__global__ __launch_bounds__(256) void k_conv_mfma(
    const short* __restrict__ ah, const short* __restrict__ al,
    const short* __restrict__ bh, const short* __restrict__ bl,
    float* __restrict__ partial, int chunk)
{
    constexpr int KTOT = CIN * 9;
    __shared__ short AsH[128][40];
    __shared__ short AsL[128][40];
    __shared__ short BsH[128][40];
    __shared__ short BsL[128][40];

    const int t     = threadIdx.x;
    const int lane  = t & 63;
    const int w     = t >> 6;
    const int wm    = (w & 1) * 64;
    const int wn    = (w >> 1) * 64;
    const int lm    = lane & 31;
    const int half  = lane >> 5;
    const int mbase = blockIdx.x * 128;
    const int kc    = blockIdx.y;
    const int k0    = kc * chunk;
    const int k1    = (k0 + chunk < KTOT) ? (k0 + chunk) : KTOT;

    int arow[2], apos[2]; bool aval[2];
    const int akc = (t & 3) * 8;
#pragma unroll
    for (int i = 0; i < 2; ++i) {
        int row = ((i * 256 + t) >> 2);
        int m   = mbase + row;
        arow[i] = row;
        aval[i] = (m < MTOT);
        int mm = aval[i] ? m : 0;
        int b  = mm / POSN;
        int p  = mm - b * POSN;
        int y  = p / OW;
        int x  = p - y * OW;
        apos[i] = b * 256 + y * STR * 16 + x * STR;
    }

    floatx16 acc[2][2];
#pragma unroll
    for (int mf = 0; mf < 2; ++mf)
#pragma unroll
        for (int nf = 0; nf < 2; ++nf)
#pragma unroll
            for (int r = 0; r < 16; ++r) acc[mf][nf][r] = 0.0f;

    const short8 zero8 = {0, 0, 0, 0, 0, 0, 0, 0};
    short8 rAh[2], rAl[2], rBh[2], rBl[2];

    auto load_stage = [&](int ks) {
        const int tap = ks / CIN;        // stage (32) never straddles a tap
        const int ci0 = ks - tap * CIN;
        const int dy  = tap / 3, dx = tap - dy * 3;
#pragma unroll
        for (int i = 0; i < 2; ++i) {
            if (aval[i]) {
                size_t g = (size_t)(apos[i] + dy * 16 + dx) * CIN + ci0 + akc;
                rAh[i] = *(const short8*)(ah + g);
                rAl[i] = *(const short8*)(al + g);
            } else { rAh[i] = zero8; rAl[i] = zero8; }
        }
#pragma unroll
        for (int i = 0; i < 2; ++i) {
            int n = ((i * 256 + t) >> 2);
            size_t g = (size_t)n * KTOT + ks + akc;
            rBh[i] = *(const short8*)(bh + g);
            rBl[i] = *(const short8*)(bl + g);
        }
    };
    auto store_stage = [&]() {
#pragma unroll
        for (int i = 0; i < 2; ++i) {
            *(short8*)&AsH[arow[i]][akc] = rAh[i];
            *(short8*)&AsL[arow[i]][akc] = rAl[i];
            int n = ((i * 256 + t) >> 2);
            *(short8*)&BsH[n][akc] = rBh[i];
            *(short8*)&BsL[n][akc] = rBl[i];
        }
    };
    auto compute = [&]() {
#pragma unroll
        for (int kst = 0; kst < 2; ++kst) {
            const int koff = kst * 16 + half * 8;
            short8 a_h[2], a_l[2], b_h[2], b_l[2];
#pragma unroll
            for (int mf = 0; mf < 2; ++mf) {
                a_h[mf] = *(const short8*)&AsH[wm + mf * 32 + lm][koff];
                a_l[mf] = *(const short8*)&AsL[wm + mf * 32 + lm][koff];
            }
#pragma unroll
            for (int nf = 0; nf < 2; ++nf) {
                b_h[nf] = *(const short8*)&BsH[wn + nf * 32 + lm][koff];
                b_l[nf] = *(const short8*)&BsL[wn + nf * 32 + lm][koff];
            }
#pragma unroll
            for (int mf = 0; mf < 2; ++mf)
#pragma unroll
                for (int nf = 0; nf < 2; ++nf) {
                    acc[mf][nf] = __builtin_amdgcn_mfma_f32_32x32x16_bf16(
                        a_h[mf], b_h[nf], acc[mf][nf], 0, 0, 0);
                    acc[mf][nf] = __builtin_amdgcn_mfma_f32_32x32x16_bf16(
                        a_h[mf], b_l[nf], acc[mf][nf], 0, 0, 0);
                    acc[mf][nf] = __builtin_amdgcn_mfma_f32_32x32x16_bf16(
                        a_l[mf], b_h[nf], acc[mf][nf], 0, 0, 0);
                }
        }
    };

    // software pipeline: global load of stage s+1 overlaps MFMA of stage s
    load_stage(k0);
    store_stage();
    for (int ks = k0 + 32; ks < k1; ks += 32) {
        __syncthreads();
        load_stage(ks);
        compute();
        __syncthreads();
        store_stage();
    }
    __syncthreads();
    compute();

    float* P = partial + (size_t)kc * MTOT * 128;
#pragma unroll
    for (int mf = 0; mf < 2; ++mf)
#pragma unroll
        for (int nf = 0; nf < 2; ++nf)
#pragma unroll
            for (int r = 0; r < 16; ++r) {
                int row = (r & 3) + 8 * (r >> 2) + 4 * half;
                int m = mbase + wm + mf * 32 + row;
                int n = wn + nf * 32 + lm;
                if (m < MTOT) P[(size_t)m * 128 + n] = acc[mf][nf][r];
            }
}

// ---- fused reduce: partials + bias + relu -> NHWC fp32 + padded bf16 hi/lo
template<int POSN, int OWV>
__global__ __launch_bounds__(256) void k_reduce_pad(const float* __restrict__ partial,
                                                    const float* __restrict__ bias,
                                                    float* __restrict__ dn,
                                                    __hip_bfloat16* __restrict__ ph,
                                                    __hip_bfloat16* __restrict__ pl,
                                                    int S)
{
    constexpr int MTOT = 8 * POSN;
    int idx = blockIdx.x * 256 + threadIdx.x;   // < 8*256*128
    int b   = idx >> 15;
    int pos = (idx >> 7) & 255;
    int co  = idx & 127;
    int y = (pos >> 4) - 1;
    int x = (pos & 15) - 1;
    if ((unsigned)y < (unsigned)OWV && (unsigned)x < (unsigned)OWV) {
        int m = b * POSN + y * OWV + x;
        float s = bias[co];
        for (int k = 0; k < S; ++k) s += partial[(size_t)k * MTOT * 128 + m * 128 + co];
        s = fmaxf(s, 0.0f);
        dn[(size_t)m * 128 + co] = s;
        __hip_bfloat16 h = __float2bfloat16(s);
        __hip_bfloat16 l = __float2bfloat16(s - __bfloat162float(h));
        ph[idx] = h; pl[idx] = l;
    } else {
        ph[idx] = __float2bfloat16(0.0f);
        pl[idx] = __float2bfloat16(0.0f);
    }
}

// ---- reduce conv3 -> NHWC fp32 [8][16][128] -------------------------------
__global__ __launch_bounds__(256) void k_reduce3(const float* __restrict__ partial,
                                                 const float* __restrict__ bias,
                                                 float* __restrict__ dn, int S)
{
    int idx = blockIdx.x * 256 + threadIdx.x;   // < 8*16*128
    int co  = idx & 127;
    float s = bias[co];
    for (int k = 0; k < S; ++k) s += partial[(size_t)k * 128 * 128 + idx];
    dn[idx] = fmaxf(s, 0.0f);
}

// ---- heads + NMS + top-6 (fused) ------------------------------------------
// Heads: 16 lanes per score (lane q holds floats [8q,8q+8)), 4 scores/wave.
// Greedy NMS truncated at 6 survivors == 6 rounds of argmax + suppress.
__global__ __launch_bounds__(256) void k_nms_topk(
    const float* __restrict__ d1n, const float* __restrict__ d2n,
    const float* __restrict__ d3n,
    const float* __restrict__ w1, const float* __restrict__ b1,
    const float* __restrict__ w2, const float* __restrict__ b2,
    const float* __restrict__ w3, const float* __restrict__ b3,
    const float* __restrict__ anchors,
    float* __restrict__ out, int* __restrict__ boxes)
{
    __shared__ float ms[NA];
    __shared__ float ay0[NA], ax0[NA], ay1[NA], ax1[NA];
    __shared__ unsigned char picked[NA];
    __shared__ float rv[4]; __shared__ int ri[4];
    __shared__ float win[5];
    int b = blockIdx.x;
    int t = threadIdx.x;
    const int wave = t >> 6;
    const int lane = t & 63;
    const int sub  = lane >> 4;      // which of 4 scores in this wave
    const int q    = lane & 15;      // 16-lane dot split

    // ---- heads: 16 scores per block-iteration (4 waves x 4 scores) ----
    for (int e0 = wave * 4; e0 < NA; e0 += 16) {
        int e = e0 + sub;
        const float* d = d3n; const float* w = w3; float bias = 0.0f;
        bool valid = (e < NA);
        if (valid) {
            if (e < 1176) {
                int c = e / 196, p = e - c * 196;
                d = d1n + (size_t)(b * 196 + p) * 128; w = w1 + c * 128; bias = b1[c];
            } else if (e < 1470) {
                int e2 = e - 1176; int c = e2 / 49, p = e2 - c * 49;
                d = d2n + (size_t)(b * 49 + p) * 128; w = w2 + c * 128; bias = b2[c];
            } else {
                int e2 = e - 1470; int c = e2 >> 4, p = e2 & 15;
                d = d3n + (size_t)(b * 16 + p) * 128; w = w3 + c * 128; bias = b3[c];
            }
        }
        float s = 0.0f;
        if (valid) {
            float4 dv0 = ((const float4*)d)[q * 2];
            float4 wv0 = ((const float4*)w)[q * 2];
            float4 dv1 = ((const float4*)d)[q * 2 + 1];
            float4 wv1 = ((const float4*)w)[q * 2 + 1];
            s = dv0.x * wv0.x;
            s = fmaf(dv0.y, wv0.y, s);
            s = fmaf(dv0.z, wv0.z, s);
            s = fmaf(dv0.w, wv0.w, s);
            s = fmaf(dv1.x, wv1.x, s);
            s = fmaf(dv1.y, wv1.y, s);
            s = fmaf(dv1.z, wv1.z, s);
            s = fmaf(dv1.w, wv1.w, s);
        }
#pragma unroll
        for (int off = 8; off > 0; off >>= 1) s += __shfl_xor(s, off);
        if (valid && q == 0) ms[e] = s + bias;
    }
    for (int i = t; i < NA; i += 256) {
        float4 an = ((const float4*)anchors)[i];
        ay0[i] = an.x; ax0[i] = an.y; ay1[i] = an.z; ax1[i] = an.w;
        picked[i] = 0;
    }
    __syncthreads();

    // ---- 6 rounds of argmax + suppress ----
    for (int r = 0; r < 6; ++r) {
        float bv = -INFINITY; int bi = NA;
        for (int i = t; i < NA; i += 256) {
            if (!picked[i]) {
                float v = ms[i];
                if (v > bv || (v == bv && i < bi)) { bv = v; bi = i; }
            }
        }
#pragma unroll
        for (int off = 32; off > 0; off >>= 1) {
            float v2 = __shfl_down(bv, off);
            int   i2 = __shfl_down(bi, off);
            if (v2 > bv || (v2 == bv && i2 < bi)) { bv = v2; bi = i2; }
        }
        if ((t & 63) == 0) { rv[t >> 6] = bv; ri[t >> 6] = bi; }
        __syncthreads();
        if (t == 0) {
            bv = rv[0]; bi = ri[0];
            for (int wv = 1; wv < 4; ++wv)
                if (rv[wv] > bv || (rv[wv] == bv && ri[wv] < bi)) { bv = rv[wv]; bi = ri[wv]; }
            picked[bi] = 1;
            win[0] = ay0[bi]; win[1] = ax0[bi]; win[2] = ay1[bi]; win[3] = ax1[bi]; win[4] = bv;
            int o = b * 6 + r;
            out[OFF_COORDS + o * 4 + 0] = ax0[bi];
            out[OFF_COORDS + o * 4 + 1] = ay0[bi];
            out[OFF_COORDS + o * 4 + 2] = ax1[bi];
            out[OFF_COORDS + o * 4 + 3] = ay1[bi];
            out[OFF_PROB + o] = bv;
            out[OFF_IDX  + o] = (float)bi;
            boxes[o * 4 + 0] = (int)ax0[bi];
            boxes[o * 4 + 1] = (int)ay0[bi];
            boxes[o * 4 + 2] = (int)ax1[bi];
            boxes[o * 4 + 3] = (int)ay1[bi];
        }
        __syncthreads();
        float by0 = win[0], bx0 = win[1], by1 = win[2], bx1 = win[3];
        float barea = (by1 - by0) * (bx1 - bx0);
        for (int i = t; i < NA; i += 256) {
            if (picked[i]) continue;
            float ih = fmaxf(fminf(by1, ay1[i]) - fmaxf(by0, ay0[i]), 0.0f);
            float iw = fmaxf(fminf(bx1, ax1[i]) - fmaxf(bx0, ax0[i]), 0.0f);
            float inter = ih * iw;
            float area  = (ay1[i] - ay0[i]) * (ax1[i] - ax0[i]);
            float iou = inter / (barea + area - inter);
            if (iou > 0.25f) ms[i] = -INFINITY;
        }
        __syncthreads();
    }
}

// ---- bilinear crop-resize, flat 1 thread = 1 px ---------------------------
__global__ __launch_bounds__(256) void k_crop(const float* __restrict__ x,
                                              const int* __restrict__ boxes,
                                              float* __restrict__ out)
{
    int lin = blockIdx.x * 256 + threadIdx.x;   // < 144*224*224
    int i    = lin % 224;
    int rest = lin / 224;
    int j    = rest % 224;
    int rc   = rest / 224;
    int c    = rc % 3;
    int br   = rc / 3;
    int b    = br / 6;
    int4 bx = ((const int4*)boxes)[br];
    float tj = (float)j / 223.0f;
    float sy = (float)bx.y + tj * (float)(bx.w - 1 - bx.y);
    int y0i = (int)floorf(sy);
    int y1i = min(y0i + 1, bx.w - 1);
    float wy = sy - (float)y0i;
    float ti = (float)i / 223.0f;
    float sx = (float)bx.x + ti * (float)(bx.z - 1 - bx.x);
    int x0i = (int)floorf(sx);
    int x1i = min(x0i + 1, bx.z - 1);
    float wx = sx - (float)x0i;
    const float* img = x + ((size_t)b * 3 + c) * 448 * 448;
    auto g = [&](int yy, int xx) -> float {
        yy -= 224; xx -= 224;
        if ((unsigned)yy >= 448u || (unsigned)xx >= 448u) return 0.0f;
        return img[(size_t)yy * 448 + xx];
    };
    float g00 = g(y0i, x0i), g01 = g(y0i, x1i);
    float g10 = g(y1i, x0i), g11 = g(y1i, x1i);
    float top = (1.0f - wx) * g00 + wx * g01;
    float bot = (1.0f - wx) * g10 + wx * g11;
    out[lin] = (1.0f - wy) * top + wy * bot;
}

// ---------------------------------------------------------------------------
extern "C" void kernel_launch(void* const* d_in, const int* in_sizes, int n_in,
                              void* d_out, int out_size, void* d_ws, size_t ws_size,
                              hipStream_t stream)
{
    (void)in_sizes; (void)n_in; (void)out_size;
    const float* x    = (const float*)d_in[0];
    const float* rpn  = (const float*)d_in[1];
    const float* anch = (const float*)d_in[2];
    const float* wd1  = (const float*)d_in[3];
    const float* bd1  = (const float*)d_in[4];
    const float* wd2  = (const float*)d_in[5];
    const float* bd2  = (const float*)d_in[6];
    const float* wd3  = (const float*)d_in[7];
    const float* bd3  = (const float*)d_in[8];
    const float* hw1  = (const float*)d_in[9];
    const float* hb1  = (const float*)d_in[10];
    const float* hw2  = (const float*)d_in[11];
    const float* hb2  = (const float*)d_in[12];
    const float* hw3  = (const float*)d_in[13];
    const float* hb3  = (const float*)d_in[14];
    float* out = (float*)d_out;

    char* ws = (char*)d_ws;
    size_t off = 0;
    auto alloc = [&](size_t bytes) -> void* {
        void* p = ws + off;
        off = (off + bytes + 255) & ~(size_t)255;
        return p;
    };
    __hip_bfloat16* ahb  = (__hip_bfloat16*)alloc((size_t)8 * 256 * 2048 * 2);
    __hip_bfloat16* alb  = (__hip_bfloat16*)alloc((size_t)8 * 256 * 2048 * 2);
    __hip_bfloat16* b1h  = (__hip_bfloat16*)alloc((size_t)128 * K1TOT * 2);
    __hip_bfloat16* b1l  = (__hip_bfloat16*)alloc((size_t)128 * K1TOT * 2);
    __hip_bfloat16* b2h  = (__hip_bfloat16*)alloc((size_t)128 * 1152 * 2);
    __hip_bfloat16* b2l  = (__hip_bfloat16*)alloc((size_t)128 * 1152 * 2);
    __hip_bfloat16* b3h  = (__hip_bfloat16*)alloc((size_t)128 * 1152 * 2);
    __hip_bfloat16* b3l  = (__hip_bfloat16*)alloc((size_t)128 * 1152 * 2);
    __hip_bfloat16* d1ph = (__hip_bfloat16*)alloc((size_t)8 * 256 * 128 * 2);
    __hip_bfloat16* d1pl = (__hip_bfloat16*)alloc((size_t)8 * 256 * 128 * 2);
    __hip_bfloat16* d2ph = (__hip_bfloat16*)alloc((size_t)8 * 256 * 128 * 2);
    __hip_bfloat16* d2pl = (__hip_bfloat16*)alloc((size_t)8 * 256 * 128 * 2);
    float* d1n  = (float*)alloc((size_t)8 * 196 * 128 * 4);
    float* d2n  = (float*)alloc((size_t)8 * 49 * 128 * 4);
    float* d3n  = (float*)alloc((size_t)8 * 16 * 128 * 4);
    int*  boxes = (int*)alloc((size_t)8 * 6 * 4 * 4);
    size_t avail = (ws_size > off) ? (ws_size - off) : 0;
    float* P = (float*)(ws + off);

    // conv1 K-split (chunk multiple of 32)
    int S1 = 48;
    if (avail < (size_t)48 * 1568 * 128 * 4) S1 = 32;
    if (avail < (size_t)32 * 1568 * 128 * 4) S1 = 16;
    int chunk1 = K1TOT / S1;        // 384 / 576 / 1152

    k_prep_all<<<dim3(3328), 256, 0, stream>>>(rpn, wd1, wd2, wd3,
        ahb, alb, b1h, b1l, b2h, b2l, b3h, b3l);

    // conv1: M=1568, CIN=2048, K-split -> partials
    k_conv_mfma<196, 14, 1, 2048, 1568><<<dim3(13, S1), 256, 0, stream>>>(
        (const short*)ahb, (const short*)alb, (const short*)b1h, (const short*)b1l,
        P, chunk1);
    k_reduce_pad<196, 14><<<dim3(1024), 256, 0, stream>>>(P, bd1, d1n, d1ph, d1pl, S1);

    // conv2: M=392, K=1152, split 3x384 (12 blocks)
    k_conv_mfma<49, 7, 2, 128, 392><<<dim3(4, 3), 256, 0, stream>>>(
        (const short*)d1ph, (const short*)d1pl, (const short*)b2h, (const short*)b2l,
        P, 384);
    k_reduce_pad<49, 7><<<dim3(1024), 256, 0, stream>>>(P, bd2, d2n, d2ph, d2pl, 3);

    // conv3: M=128, K=1152, split 3x384 (3 blocks)
    k_conv_mfma<16, 4, 2, 128, 128><<<dim3(1, 3), 256, 0, stream>>>(
        (const short*)d2ph, (const short*)d2pl, (const short*)b3h, (const short*)b3l,
        P, 384);
    k_reduce3<<<dim3(64), 256, 0, stream>>>(P, bd3, d3n, 3);

    // heads + NMS + top6 (fused, wave-parallel dots)
    k_nms_topk<<<dim3(8), 256, 0, stream>>>(d1n, d2n, d3n,
        hw1, hb1, hw2, hb2, hw3, hb3, anch, out, boxes);

    k_crop<<<dim3(28224), 256, 0, stream>>>(x, boxes, out);
}

// Round 7
// 265.742 us; speedup vs baseline: 1.3086x; 1.1472x over previous
//
#include <hip/hip_runtime.h>
#include <hip/hip_bf16.h>
#include <math.h>
#include <stdint.h>

// ---------------------------------------------------------------------------
// attention_net (MI355X gfx950)
//   conv1: 2048->128 14x14 s1p1 | conv2: 128->128 ->7x7 s2p1 | conv3: ->4x4
//   All convs: split-bf16 (hi+lo) MFMA 32x32x16, NHWC padded-16x16 A,
//   software-pipelined K loop. K-split partials + reduce epilogues.
//   heads: separate high-TLP kernel (208 blocks). NMS: 8 blocks, LDS-local.
// Output floats: part_imgs[7225344], coords[192], top_prob[48], top_idx[48]
// ---------------------------------------------------------------------------

#define OFF_COORDS 7225344
#define OFF_PROB   7225536
#define OFF_IDX    7225584
#define NA 1614
#define K1TOT 18432

typedef __attribute__((ext_vector_type(8)))  short  short8;
typedef __attribute__((ext_vector_type(16))) float  floatx16;

// ---- unified prep: conv1 A + conv1 B + conv2/3 B --------------------------
__global__ __launch_bounds__(256) void k_prep_all(
    const float* __restrict__ rpn,
    const float* __restrict__ wd1,
    const float* __restrict__ wd2,
    const float* __restrict__ wd3,
    __hip_bfloat16* __restrict__ ah,  __hip_bfloat16* __restrict__ al,
    __hip_bfloat16* __restrict__ b1h, __hip_bfloat16* __restrict__ b1l,
    __hip_bfloat16* __restrict__ b2h, __hip_bfloat16* __restrict__ b2l,
    __hip_bfloat16* __restrict__ b3h, __hip_bfloat16* __restrict__ b3l)
{
    const int bid = blockIdx.x;
    const int t   = threadIdx.x;
    if (bid < 1024) {
        __shared__ float tile[64][65];
        const int cib  = (bid & 31) * 64;
        const int posb = ((bid >> 5) & 3) * 64;
        const int b    = bid >> 7;
#pragma unroll
        for (int it = 0; it < 16; ++it) {
            int idx  = it * 256 + t;
            int cil  = idx >> 6;
            int posl = idx & 63;
            int pos  = posb + posl;
            int py = pos >> 4, px = pos & 15;
            int y = py - 1, x = px - 1;
            float v = 0.0f;
            if ((unsigned)y < 14u && (unsigned)x < 14u)
                v = rpn[((size_t)(b * 2048 + cib + cil) * 14 + y) * 14 + x];
            tile[cil][posl] = v;
        }
        __syncthreads();
#pragma unroll
        for (int it = 0; it < 16; ++it) {
            int idx  = it * 256 + t;
            int posl = idx >> 6;
            int cil  = idx & 63;
            float v = tile[cil][posl];
            __hip_bfloat16 h = __float2bfloat16(v);
            __hip_bfloat16 l = __float2bfloat16(v - __bfloat162float(h));
            size_t o = (size_t)(b * 256 + posb + posl) * 2048 + cib + cil;
            ah[o] = h; al[o] = l;
        }
    } else if (bid < 2176) {
        int local = bid - 1024;
        int tap = local % 9;
        int co  = local / 9;
#pragma unroll
        for (int i = 0; i < 8; ++i) {
            int ci = i * 256 + t;
            float v = wd1[((size_t)co * 2048 + ci) * 9 + tap];
            __hip_bfloat16 h = __float2bfloat16(v);
            __hip_bfloat16 l = __float2bfloat16(v - __bfloat162float(h));
            size_t o = (size_t)co * K1TOT + tap * 2048 + ci;
            b1h[o] = h; b1l[o] = l;
        }
    } else {
        int local = bid - 2176;          // 0..1151
        int z  = local >= 576;
        int l3 = z ? (local - 576) : local;
        int tap = l3 % 9;
        int co  = (l3 / 9) * 2 + (t >> 7);
        int ci  = t & 127;
        const float* w = z ? wd3 : wd2;
        __hip_bfloat16* bh = z ? b3h : b2h;
        __hip_bfloat16* bl = z ? b3l : b2l;
        float v = w[((size_t)co * 128 + ci) * 9 + tap];
        __hip_bfloat16 h = __float2bfloat16(v);
        __hip_bfloat16 l = __float2bfloat16(v - __bfloat162float(h));
        size_t o = (size_t)co * 1152 + tap * 128 + ci;
        bh[o] = h; bl[o] = l;
    }
}

// ---- unified split-bf16 MFMA implicit-GEMM conv, software-pipelined -------
template<int POSN, int OW, int STR, int CIN, int MTOT>
__global__ __launch_bounds__(256) void k_conv_mfma(
    const short* __restrict__ ah, const short* __restrict__ al,
    const short* __restrict__ bh, const short* __restrict__ bl,
    float* __restrict__ partial, int chunk)
{
    constexpr int KTOT = CIN * 9;
    __shared__ short AsH[128][40];
    __shared__ short AsL[128][40];
    __shared__ short BsH[128][40];
    __shared__ short BsL[128][40];

    const int t     = threadIdx.x;
    const int lane  = t & 63;
    const int w     = t >> 6;
    const int wm    = (w & 1) * 64;
    const int wn    = (w >> 1) * 64;
    const int lm    = lane & 31;
    const int half  = lane >> 5;
    const int mbase = blockIdx.x * 128;
    const int kc    = blockIdx.y;
    const int k0    = kc * chunk;
    const int k1    = (k0 + chunk < KTOT) ? (k0 + chunk) : KTOT;

    int arow[2], apos[2]; bool aval[2];
    const int akc = (t & 3) * 8;
#pragma unroll
    for (int i = 0; i < 2; ++i) {
        int row = ((i * 256 + t) >> 2);
        int m   = mbase + row;
        arow[i] = row;
        aval[i] = (m < MTOT);
        int mm = aval[i] ? m : 0;
        int b  = mm / POSN;
        int p  = mm - b * POSN;
        int y  = p / OW;
        int x  = p - y * OW;
        apos[i] = b * 256 + y * STR * 16 + x * STR;
    }

    floatx16 acc[2][2];
#pragma unroll
    for (int mf = 0; mf < 2; ++mf)
#pragma unroll
        for (int nf = 0; nf < 2; ++nf)
#pragma unroll
            for (int r = 0; r < 16; ++r) acc[mf][nf][r] = 0.0f;

    const short8 zero8 = {0, 0, 0, 0, 0, 0, 0, 0};
    short8 rAh[2], rAl[2], rBh[2], rBl[2];

    auto load_stage = [&](int ks) {
        const int tap = ks / CIN;
        const int ci0 = ks - tap * CIN;
        const int dy  = tap / 3, dx = tap - dy * 3;
#pragma unroll
        for (int i = 0; i < 2; ++i) {
            if (aval[i]) {
                size_t g = (size_t)(apos[i] + dy * 16 + dx) * CIN + ci0 + akc;
                rAh[i] = *(const short8*)(ah + g);
                rAl[i] = *(const short8*)(al + g);
            } else { rAh[i] = zero8; rAl[i] = zero8; }
        }
#pragma unroll
        for (int i = 0; i < 2; ++i) {
            int n = ((i * 256 + t) >> 2);
            size_t g = (size_t)n * KTOT + ks + akc;
            rBh[i] = *(const short8*)(bh + g);
            rBl[i] = *(const short8*)(bl + g);
        }
    };
    auto store_stage = [&]() {
#pragma unroll
        for (int i = 0; i < 2; ++i) {
            *(short8*)&AsH[arow[i]][akc] = rAh[i];
            *(short8*)&AsL[arow[i]][akc] = rAl[i];
            int n = ((i * 256 + t) >> 2);
            *(short8*)&BsH[n][akc] = rBh[i];
            *(short8*)&BsL[n][akc] = rBl[i];
        }
    };
    auto compute = [&]() {
#pragma unroll
        for (int kst = 0; kst < 2; ++kst) {
            const int koff = kst * 16 + half * 8;
            short8 a_h[2], a_l[2], b_h[2], b_l[2];
#pragma unroll
            for (int mf = 0; mf < 2; ++mf) {
                a_h[mf] = *(const short8*)&AsH[wm + mf * 32 + lm][koff];
                a_l[mf] = *(const short8*)&AsL[wm + mf * 32 + lm][koff];
            }
#pragma unroll
            for (int nf = 0; nf < 2; ++nf) {
                b_h[nf] = *(const short8*)&BsH[wn + nf * 32 + lm][koff];
                b_l[nf] = *(const short8*)&BsL[wn + nf * 32 + lm][koff];
            }
#pragma unroll
            for (int mf = 0; mf < 2; ++mf)
#pragma unroll
                for (int nf = 0; nf < 2; ++nf) {
                    acc[mf][nf] = __builtin_amdgcn_mfma_f32_32x32x16_bf16(
                        a_h[mf], b_h[nf], acc[mf][nf], 0, 0, 0);
                    acc[mf][nf] = __builtin_amdgcn_mfma_f32_32x32x16_bf16(
                        a_h[mf], b_l[nf], acc[mf][nf], 0, 0, 0);
                    acc[mf][nf] = __builtin_amdgcn_mfma_f32_32x32x16_bf16(
                        a_l[mf], b_h[nf], acc[mf][nf], 0, 0, 0);
                }
        }
    };

    load_stage(k0);
    store_stage();
    for (int ks = k0 + 32; ks < k1; ks += 32) {
        __syncthreads();
        load_stage(ks);
        compute();
        __syncthreads();
        store_stage();
    }
    __syncthreads();
    compute();

    float* P = partial + (size_t)kc * MTOT * 128;
#pragma unroll
    for (int mf = 0; mf < 2; ++mf)
#pragma unroll
        for (int nf = 0; nf < 2; ++nf)
#pragma unroll
            for (int r = 0; r < 16; ++r) {
                int row = (r & 3) + 8 * (r >> 2) + 4 * half;
                int m = mbase + wm + mf * 32 + row;
                int n = wn + nf * 32 + lm;
                if (m < MTOT) P[(size_t)m * 128 + n] = acc[mf][nf][r];
            }
}

// ---- fused reduce: partials + bias + relu -> NHWC fp32 + padded bf16 hi/lo
template<int POSN, int OWV>
__global__ __launch_bounds__(256) void k_reduce_pad(const float* __restrict__ partial,
                                                    const float* __restrict__ bias,
                                                    float* __restrict__ dn,
                                                    __hip_bfloat16* __restrict__ ph,
                                                    __hip_bfloat16* __restrict__ pl,
                                                    int S)
{
    constexpr int MTOT = 8 * POSN;
    int idx = blockIdx.x * 256 + threadIdx.x;   // < 8*256*128
    int b   = idx >> 15;
    int pos = (idx >> 7) & 255;
    int co  = idx & 127;
    int y = (pos >> 4) - 1;
    int x = (pos & 15) - 1;
    if ((unsigned)y < (unsigned)OWV && (unsigned)x < (unsigned)OWV) {
        int m = b * POSN + y * OWV + x;
        float s = bias[co];
        for (int k = 0; k < S; ++k) s += partial[(size_t)k * MTOT * 128 + m * 128 + co];
        s = fmaxf(s, 0.0f);
        dn[(size_t)m * 128 + co] = s;
        __hip_bfloat16 h = __float2bfloat16(s);
        __hip_bfloat16 l = __float2bfloat16(s - __bfloat162float(h));
        ph[idx] = h; pl[idx] = l;
    } else {
        ph[idx] = __float2bfloat16(0.0f);
        pl[idx] = __float2bfloat16(0.0f);
    }
}

// ---- reduce conv3 -> NHWC fp32 [8][16][128] -------------------------------
__global__ __launch_bounds__(256) void k_reduce3(const float* __restrict__ partial,
                                                 const float* __restrict__ bias,
                                                 float* __restrict__ dn, int S)
{
    int idx = blockIdx.x * 256 + threadIdx.x;   // < 8*16*128
    int co  = idx & 127;
    float s = bias[co];
    for (int k = 0; k < S; ++k) s += partial[(size_t)k * 128 * 128 + idx];
    dn[idx] = fmaxf(s, 0.0f);
}

// ---- heads: high-TLP score kernel. grid (26, 8); 64 scores/block, 4 lanes each
__global__ __launch_bounds__(256) void k_heads(
    const float* __restrict__ d1n, const float* __restrict__ d2n,
    const float* __restrict__ d3n,
    const float* __restrict__ w1, const float* __restrict__ b1,
    const float* __restrict__ w2, const float* __restrict__ b2,
    const float* __restrict__ w3, const float* __restrict__ b3,
    float* __restrict__ sc)
{
    int b = blockIdx.y;
    int e = blockIdx.x * 64 + (threadIdx.x >> 2);
    int q = threadIdx.x & 3;
    if (e >= NA) return;
    const float* d; const float* w; float bias;
    if (e < 1176) {
        int c = e / 196, p = e - c * 196;
        d = d1n + (size_t)(b * 196 + p) * 128; w = w1 + c * 128; bias = b1[c];
    } else if (e < 1470) {
        int e2 = e - 1176; int c = e2 / 49, p = e2 - c * 49;
        d = d2n + (size_t)(b * 49 + p) * 128; w = w2 + c * 128; bias = b2[c];
    } else {
        int e2 = e - 1470; int c = e2 >> 4, p = e2 & 15;
        d = d3n + (size_t)(b * 16 + p) * 128; w = w3 + c * 128; bias = b3[c];
    }
    float s = 0.0f;
#pragma unroll
    for (int i = 0; i < 8; ++i) {
        float4 dv = ((const float4*)d)[q * 8 + i];
        float4 wv = ((const float4*)w)[q * 8 + i];
        s = fmaf(dv.x, wv.x, s);
        s = fmaf(dv.y, wv.y, s);
        s = fmaf(dv.z, wv.z, s);
        s = fmaf(dv.w, wv.w, s);
    }
    s += __shfl_xor(s, 1);
    s += __shfl_xor(s, 2);
    if (q == 0) sc[b * NA + e] = s + bias;
}

// ---- NMS + top-6 (greedy NMS truncated at 6 == 6x argmax+suppress) --------
__global__ __launch_bounds__(256) void k_nms_topk(const float* __restrict__ scores,
                                                  const float* __restrict__ anchors,
                                                  float* __restrict__ out,
                                                  int* __restrict__ boxes)
{
    __shared__ float ms[NA];
    __shared__ float ay0[NA], ax0[NA], ay1[NA], ax1[NA];
    __shared__ unsigned char picked[NA];
    __shared__ float rv[4]; __shared__ int ri[4];
    __shared__ float win[5];
    int b = blockIdx.x;
    int t = threadIdx.x;
    for (int i = t; i < NA; i += 256) {
        ms[i] = scores[b * NA + i];
        float4 an = ((const float4*)anchors)[i];
        ay0[i] = an.x; ax0[i] = an.y; ay1[i] = an.z; ax1[i] = an.w;
        picked[i] = 0;
    }
    __syncthreads();
    for (int r = 0; r < 6; ++r) {
        float bv = -INFINITY; int bi = NA;
        for (int i = t; i < NA; i += 256) {
            if (!picked[i]) {
                float v = ms[i];
                if (v > bv || (v == bv && i < bi)) { bv = v; bi = i; }
            }
        }
#pragma unroll
        for (int off = 32; off > 0; off >>= 1) {
            float v2 = __shfl_down(bv, off);
            int   i2 = __shfl_down(bi, off);
            if (v2 > bv || (v2 == bv && i2 < bi)) { bv = v2; bi = i2; }
        }
        if ((t & 63) == 0) { rv[t >> 6] = bv; ri[t >> 6] = bi; }
        __syncthreads();
        if (t == 0) {
            bv = rv[0]; bi = ri[0];
            for (int wv = 1; wv < 4; ++wv)
                if (rv[wv] > bv || (rv[wv] == bv && ri[wv] < bi)) { bv = rv[wv]; bi = ri[wv]; }
            picked[bi] = 1;
            win[0] = ay0[bi]; win[1] = ax0[bi]; win[2] = ay1[bi]; win[3] = ax1[bi]; win[4] = bv;
            int o = b * 6 + r;
            out[OFF_COORDS + o * 4 + 0] = ax0[bi];
            out[OFF_COORDS + o * 4 + 1] = ay0[bi];
            out[OFF_COORDS + o * 4 + 2] = ax1[bi];
            out[OFF_COORDS + o * 4 + 3] = ay1[bi];
            out[OFF_PROB + o] = bv;
            out[OFF_IDX  + o] = (float)bi;
            boxes[o * 4 + 0] = (int)ax0[bi];
            boxes[o * 4 + 1] = (int)ay0[bi];
            boxes[o * 4 + 2] = (int)ax1[bi];
            boxes[o * 4 + 3] = (int)ay1[bi];
        }
        __syncthreads();
        float by0 = win[0], bx0 = win[1], by1 = win[2], bx1 = win[3];
        float barea = (by1 - by0) * (bx1 - bx0);
        for (int i = t; i < NA; i += 256) {
            if (picked[i]) continue;
            float ih = fmaxf(fminf(by1, ay1[i]) - fmaxf(by0, ay0[i]), 0.0f);
            float iw = fmaxf(fminf(bx1, ax1[i]) - fmaxf(bx0, ax0[i]), 0.0f);
            float inter = ih * iw;
            float area  = (ay1[i] - ay0[i]) * (ax1[i] - ax0[i]);
            float iou = inter / (barea + area - inter);
            if (iou > 0.25f) ms[i] = -INFINITY;
        }
        __syncthreads();
    }
}

// ---- bilinear crop-resize, flat 1 thread = 1 px ---------------------------
__global__ __launch_bounds__(256) void k_crop(const float* __restrict__ x,
                                              const int* __restrict__ boxes,
                                              float* __restrict__ out)
{
    int lin = blockIdx.x * 256 + threadIdx.x;   // < 144*224*224
    int i    = lin % 224;
    int rest = lin / 224;
    int j    = rest % 224;
    int rc   = rest / 224;
    int c    = rc % 3;
    int br   = rc / 3;
    int b    = br / 6;
    int4 bx = ((const int4*)boxes)[br];
    float tj = (float)j / 223.0f;
    float sy = (float)bx.y + tj * (float)(bx.w - 1 - bx.y);
    int y0i = (int)floorf(sy);
    int y1i = min(y0i + 1, bx.w - 1);
    float wy = sy - (float)y0i;
    float ti = (float)i / 223.0f;
    float sx = (float)bx.x + ti * (float)(bx.z - 1 - bx.x);
    int x0i = (int)floorf(sx);
    int x1i = min(x0i + 1, bx.z - 1);
    float wx = sx - (float)x0i;
    const float* img = x + ((size_t)b * 3 + c) * 448 * 448;
    auto g = [&](int yy, int xx) -> float {
        yy -= 224; xx -= 224;
        if ((unsigned)yy >= 448u || (unsigned)xx >= 448u) return 0.0f;
        return img[(size_t)yy * 448 + xx];
    };
    float g00 = g(y0i, x0i), g01 = g(y0i, x1i);
    float g10 = g(y1i, x0i), g11 = g(y1i, x1i);
    float top = (1.0f - wx) * g00 + wx * g01;
    float bot = (1.0f - wx) * g10 + wx * g11;
    out[lin] = (1.0f - wy) * top + wy * bot;
}

// ---------------------------------------------------------------------------
extern "C" void kernel_launch(void* const* d_in, const int* in_sizes, int n_in,
                              void* d_out, int out_size, void* d_ws, size_t ws_size,
                              hipStream_t stream)
{
    (void)in_sizes; (void)n_in; (void)out_size;
    const float* x    = (const float*)d_in[0];
    const float* rpn  = (const float*)d_in[1];
    const float* anch = (const float*)d_in[2];
    const float* wd1  = (const float*)d_in[3];
    const float* bd1  = (const float*)d_in[4];
    const float* wd2  = (const float*)d_in[5];
    const float* bd2  = (const float*)d_in[6];
    const float* wd3  = (const float*)d_in[7];
    const float* bd3  = (const float*)d_in[8];
    const float* hw1  = (const float*)d_in[9];
    const float* hb1  = (const float*)d_in[10];
    const float* hw2  = (const float*)d_in[11];
    const float* hb2  = (const float*)d_in[12];
    const float* hw3  = (const float*)d_in[13];
    const float* hb3  = (const float*)d_in[14];
    float* out = (float*)d_out;

    char* ws = (char*)d_ws;
    size_t off = 0;
    auto alloc = [&](size_t bytes) -> void* {
        void* p = ws + off;
        off = (off + bytes + 255) & ~(size_t)255;
        return p;
    };
    __hip_bfloat16* ahb  = (__hip_bfloat16*)alloc((size_t)8 * 256 * 2048 * 2);
    __hip_bfloat16* alb  = (__hip_bfloat16*)alloc((size_t)8 * 256 * 2048 * 2);
    __hip_bfloat16* b1h  = (__hip_bfloat16*)alloc((size_t)128 * K1TOT * 2);
    __hip_bfloat16* b1l  = (__hip_bfloat16*)alloc((size_t)128 * K1TOT * 2);
    __hip_bfloat16* b2h  = (__hip_bfloat16*)alloc((size_t)128 * 1152 * 2);
    __hip_bfloat16* b2l  = (__hip_bfloat16*)alloc((size_t)128 * 1152 * 2);
    __hip_bfloat16* b3h  = (__hip_bfloat16*)alloc((size_t)128 * 1152 * 2);
    __hip_bfloat16* b3l  = (__hip_bfloat16*)alloc((size_t)128 * 1152 * 2);
    __hip_bfloat16* d1ph = (__hip_bfloat16*)alloc((size_t)8 * 256 * 128 * 2);
    __hip_bfloat16* d1pl = (__hip_bfloat16*)alloc((size_t)8 * 256 * 128 * 2);
    __hip_bfloat16* d2ph = (__hip_bfloat16*)alloc((size_t)8 * 256 * 128 * 2);
    __hip_bfloat16* d2pl = (__hip_bfloat16*)alloc((size_t)8 * 256 * 128 * 2);
    float* d1n  = (float*)alloc((size_t)8 * 196 * 128 * 4);
    float* d2n  = (float*)alloc((size_t)8 * 49 * 128 * 4);
    float* d3n  = (float*)alloc((size_t)8 * 16 * 128 * 4);
    float* sc   = (float*)alloc((size_t)8 * NA * 4);
    int*  boxes = (int*)alloc((size_t)8 * 6 * 4 * 4);
    size_t avail = (ws_size > off) ? (ws_size - off) : 0;
    float* P = (float*)(ws + off);

    int S1 = 48;
    if (avail < (size_t)48 * 1568 * 128 * 4) S1 = 32;
    if (avail < (size_t)32 * 1568 * 128 * 4) S1 = 16;
    int chunk1 = K1TOT / S1;        // 384 / 576 / 1152

    k_prep_all<<<dim3(3328), 256, 0, stream>>>(rpn, wd1, wd2, wd3,
        ahb, alb, b1h, b1l, b2h, b2l, b3h, b3l);

    // conv1: M=1568, CIN=2048, K-split -> partials
    k_conv_mfma<196, 14, 1, 2048, 1568><<<dim3(13, S1), 256, 0, stream>>>(
        (const short*)ahb, (const short*)alb, (const short*)b1h, (const short*)b1l,
        P, chunk1);
    k_reduce_pad<196, 14><<<dim3(1024), 256, 0, stream>>>(P, bd1, d1n, d1ph, d1pl, S1);

    // conv2: M=392, K=1152, split 3x384 (12 blocks)
    k_conv_mfma<49, 7, 2, 128, 392><<<dim3(4, 3), 256, 0, stream>>>(
        (const short*)d1ph, (const short*)d1pl, (const short*)b2h, (const short*)b2l,
        P, 384);
    k_reduce_pad<49, 7><<<dim3(1024), 256, 0, stream>>>(P, bd2, d2n, d2ph, d2pl, 3);

    // conv3: M=128, K=1152, split 3x384 (3 blocks)
    k_conv_mfma<16, 4, 2, 128, 128><<<dim3(1, 3), 256, 0, stream>>>(
        (const short*)d2ph, (const short*)d2pl, (const short*)b3h, (const short*)b3l,
        P, 384);
    k_reduce3<<<dim3(64), 256, 0, stream>>>(P, bd3, d3n, 3);

    // heads: high-TLP (208 blocks)
    k_heads<<<dim3(26, 8), 256, 0, stream>>>(d1n, d2n, d3n,
        hw1, hb1, hw2, hb2, hw3, hb3, sc);

    k_nms_topk<<<dim3(8), 256, 0, stream>>>(sc, anch, out, boxes);
    k_crop<<<dim3(28224), 256, 0, stream>>>(x, boxes, out);
}